// Round 1
// baseline (654.658 us; speedup 1.0000x reference)
//
#include <hip/hip_runtime.h>
#include <math.h>

// Problem constants (B=4, H=16, S=4096, D=64, m=256)
#define DNORM   0.35355339059327376f   // sqrt(softmax_temp) = (1/8)^0.5
#define DIAG_F  0.0625f                // 0.5 * softmax_temp = 0.5/8
#define HLM     2.772588722239781f     // log(256)/2
#define ROWS_TOTAL   262144            // B*H*S
#define ROWS_PER_BH  4096              // S
#define FEAT_ELEMS   67108864          // B*H*S*256

// LDS projection tile: 128 rows x 16 float4 chunks (32 KiB), chunk-XOR swizzled
// so that per-wave reads pd[l][c^ (l&15)] hit 16 distinct addresses spread over
// 8 bank groups (2-way aliasing = free on CDNA4).
__device__ __forceinline__ void load_proj(const float* __restrict__ proj,
                                          float4 (*pd)[16], int tid) {
    const float4* p4 = reinterpret_cast<const float4*>(proj);
#pragma unroll
    for (int i = 0; i < 8; ++i) {
        int idx = tid + i * 256;          // 0..2047
        int j = idx >> 4;                 // proj row 0..127
        int c = idx & 15;                 // chunk 0..15
        float4 v = p4[idx];
        v.x *= DNORM; v.y *= DNORM; v.z *= DNORM; v.w *= DNORM;
        pd[j][c ^ (j & 15)] = v;
    }
}

// One wave computes one data row: x0 = x[lane], x1 = x[lane+64] (the 128
// projections), plus diag = sum(row^2) * 0.0625 (wave-uniform).
__device__ __forceinline__ void row_xdiag(const float* __restrict__ data,
                                          size_t row, const float4 (*pd)[16],
                                          int l, float& x0, float& x1,
                                          float& diag) {
    // diag: one coalesced element per lane, butterfly-sum across 64 lanes
    float v = data[row * 64 + l];
    float dd = v * v;
#pragma unroll
    for (int s = 32; s; s >>= 1) dd += __shfl_xor(dd, s, 64);
    diag = dd * DIAG_F;

    const float4* row4 = reinterpret_cast<const float4*>(data + row * 64);
    int lx = l & 15;
    x0 = 0.f; x1 = 0.f;
#pragma unroll
    for (int c = 0; c < 16; ++c) {
        float4 r  = row4[c];              // wave-uniform address -> broadcast
        float4 p0 = pd[l][c ^ lx];
        float4 p1 = pd[l + 64][c ^ lx];
        x0 = fmaf(r.w, p0.w, fmaf(r.z, p0.z, fmaf(r.y, p0.y, fmaf(r.x, p0.x, x0))));
        x1 = fmaf(r.w, p1.w, fmaf(r.z, p1.z, fmaf(r.y, p1.y, fmaf(r.x, p1.x, x1))));
    }
}

__device__ __forceinline__ float wave_max(float m) {
#pragma unroll
    for (int s = 32; s; s >>= 1) m = fmaxf(m, __shfl_xor(m, s, 64));
    return m;
}

// Pass 1 for k: per-block max of (max_j |x_j| - diag - hlm) over 64 rows.
__global__ __launch_bounds__(256) void kmax_kernel(const float* __restrict__ k,
                                                   const float* __restrict__ proj,
                                                   float* __restrict__ partials) {
    __shared__ float4 pd[128][16];
    __shared__ float red[4];
    int tid = threadIdx.x;
    load_proj(proj, pd, tid);
    __syncthreads();
    int wave = tid >> 6, l = tid & 63;
    size_t row0 = (size_t)blockIdx.x * 64 + wave * 16;
    float wmax = -INFINITY;
    for (int i = 0; i < 16; ++i) {
        float x0, x1, diag;
        row_xdiag(k, row0 + i, pd, l, x0, x1, diag);
        float m = wave_max(fmaxf(fabsf(x0), fabsf(x1)));
        wmax = fmaxf(wmax, m - diag - HLM);
    }
    if (l == 0) red[wave] = wmax;
    __syncthreads();
    if (tid == 0)
        partials[blockIdx.x] =
            fmaxf(fmaxf(red[0], red[1]), fmaxf(red[2], red[3]));
}

// Reduce 64 block-partials per (b,h) -> k_log_scale[64]
__global__ void kmax_reduce(const float* __restrict__ partials,
                            float* __restrict__ kls) {
    int bh = threadIdx.x;  // 0..63
    float m = -INFINITY;
    for (int i = 0; i < 64; ++i) m = fmaxf(m, partials[bh * 64 + i]);
    kls[bh] = m;
}

// q features + per-row log scale
__global__ __launch_bounds__(256) void qfeat_kernel(const float* __restrict__ q,
                                                    const float* __restrict__ proj,
                                                    float* __restrict__ qf,
                                                    float* __restrict__ qls) {
    __shared__ float4 pd[128][16];
    int tid = threadIdx.x;
    load_proj(proj, pd, tid);
    __syncthreads();
    int wave = tid >> 6, l = tid & 63;
    size_t row0 = (size_t)blockIdx.x * 64 + wave * 16;
    for (int i = 0; i < 16; ++i) {
        size_t row = row0 + i;
        float x0, x1, diag;
        row_xdiag(q, row, pd, l, x0, x1, diag);
        float amax = wave_max(fmaxf(fabsf(x0), fabsf(x1)));
        float e0 = __expf(x0 - amax);
        float e1 = __expf(x1 - amax);
        float e2 = __expf(-x0 - amax);
        float e3 = __expf(-x1 - amax);
        float* o = qf + row * 256 + l;
        o[0] = e0; o[64] = e1; o[128] = e2; o[192] = e3;
        if (l == 0) qls[row] = amax - diag - HLM;
    }
}

// k features using the global per-(b,h) log scale
__global__ __launch_bounds__(256) void kfeat_kernel(const float* __restrict__ k,
                                                    const float* __restrict__ proj,
                                                    float* __restrict__ kf,
                                                    const float* __restrict__ kls) {
    __shared__ float4 pd[128][16];
    int tid = threadIdx.x;
    load_proj(proj, pd, tid);
    __syncthreads();
    float gls = kls[blockIdx.x >> 6];  // 64 blocks per (b,h)
    int wave = tid >> 6, l = tid & 63;
    size_t row0 = (size_t)blockIdx.x * 64 + wave * 16;
    for (int i = 0; i < 16; ++i) {
        size_t row = row0 + i;
        float x0, x1, diag;
        row_xdiag(k, row, pd, l, x0, x1, diag);
        float off = diag + HLM + gls;
        float e0 = __expf(x0 - off);
        float e1 = __expf(x1 - off);
        float e2 = __expf(-x0 - off);
        float e3 = __expf(-x1 - off);
        float* o = kf + row * 256 + l;
        o[0] = e0; o[64] = e1; o[128] = e2; o[192] = e3;
    }
}

extern "C" void kernel_launch(void* const* d_in, const int* in_sizes, int n_in,
                              void* d_out, int out_size, void* d_ws, size_t ws_size,
                              hipStream_t stream) {
    const float* q    = (const float*)d_in[0];
    const float* k    = (const float*)d_in[1];
    const float* proj = (const float*)d_in[2];

    float* out = (float*)d_out;
    float* qf  = out;                                   // (B,H,S,256)
    float* qls = out + (size_t)FEAT_ELEMS;              // (B,H,S,1)
    float* kf  = out + (size_t)FEAT_ELEMS + ROWS_TOTAL; // (B,H,S,256)
    float* kls = out + 2 * (size_t)FEAT_ELEMS + ROWS_TOTAL; // (B,H,1,1)

    // 4096 float partials; fall back to the (later fully overwritten) k_feats
    // region if the workspace is too small.
    float* partials = (ws_size >= 4096 * sizeof(float)) ? (float*)d_ws : kf;

    const int blocks = ROWS_TOTAL / 64;  // 4096
    kmax_kernel <<<blocks, 256, 0, stream>>>(k, proj, partials);
    kmax_reduce <<<1, 64, 0, stream>>>(partials, kls);
    qfeat_kernel<<<blocks, 256, 0, stream>>>(q, proj, qf, qls);
    kfeat_kernel<<<blocks, 256, 0, stream>>>(k, proj, kf, kls);
}